// Round 3
// baseline (259.424 us; speedup 1.0000x reference)
//
#include <hip/hip_runtime.h>

// LSTM: B=2048, T=512, I=6, H=50, O=3. fp32 in/out, bf16 MFMA inner matmul.
//
// R6: serial-chain surgery. Time = 512 x per-step chain (parallelism can't
// help: every step depends on all h of the previous). Cuts vs R5:
//  - Broadcast-B: bfr reads use row (col&7) -> batch cols duplicated into
//    cols 8..15, so EVERY lane holds a valid (b,hh) quad for EVERY tile.
//    Redistribution = 8 cndmask (select acc[0]/acc[1]), no shfl, no LDS
//    round-trip. Also makes the b128 reads conflict-free (8 addrs x 2-way
//    broadcast per 16-lane phase; AP=72 -> start banks 4b, full coverage).
//  - 4-wave WG (256 thr, grid=256 = 1 WG/CU, 1 wave/SIMD): removes the
//    ~150cy second-wave-per-SIMD barrier straggle. 4 tiles/wave (unused
//    tiles zero-padded -> uniform code, balanced waves).
//  - x-part off-chain: accx[ti] = mfma(wfx, Xpack[t+1]) issued during step
//    t (h-independent); it is the C-input of step t+1's h-MFMAs. Deletes
//    per-step acc zero-init + the divergent quad2/Xpack address select.
//    k' layout: 0..49 = h (pure), x/bias live in accx's own k-space.
//  - Fused cell: sig(i)*tanh(g) = (eg-1)*rcp((1+ei)(1+eg)) -> 8 transcend.
//    per pair (was 10), clamps +-115 keep (e-1) finite (no inf*0 NaN).
// 1 barrier/step; c-state in registers; weights pre-scaled by L2E / 2*L2E.

#define L2E 1.44269504088896340736f

typedef float  f32x4 __attribute__((ext_vector_type(4)));
typedef short  s16x8 __attribute__((ext_vector_type(8)));   // 8 bf16 bit-patterns

__device__ __forceinline__ float fast_exp2(float x){ return __builtin_amdgcn_exp2f(x); }
__device__ __forceinline__ float fast_rcp (float x){ return __builtin_amdgcn_rcpf(x); }

// float -> bf16 bits, round-to-nearest-even
__device__ __forceinline__ unsigned short f2bf(float f){
  unsigned u = __builtin_bit_cast(unsigned, f);
  u = (u + 0x7FFFu + ((u >> 16) & 1u)) >> 16;
  return (unsigned short)u;
}

// gates pre-scaled: g[0,1,3] = L2E*(i,f,o), g[2] = 2*L2E*g. Updates c,
// returns h. 8 transcendentals (5 exp2 + 3 rcp).
__device__ __forceinline__ float lstm_cell(const f32x4 g, float& c){
  const float ef = fast_exp2(-g[1]);
  const float sf = fast_rcp(1.0f + ef);                    // sigmoid(f)
  const float yg = fminf(fmaxf(g[2], -115.f), 115.f);
  const float eg = fast_exp2(yg);
  const float ei = fast_exp2(-g[0]);
  const float r1 = fast_rcp((1.0f + ei) * (1.0f + eg));
  c = sf * c + (eg - 1.0f) * r1;                           // f*c + sig(i)*tanh(g)
  const float yc = fminf(fmaxf(c * (2.0f * L2E), -115.f), 115.f);
  const float ec = fast_exp2(yc);
  const float eo = fast_exp2(-g[3]);
  const float r2 = fast_rcp((1.0f + eo) * (1.0f + ec));
  return (ec - 1.0f) * r2;                                 // sig(o)*tanh(c)
}

constexpr int B_ = 2048, T_ = 512, I_ = 6, H_ = 50;
constexpr int NB = 8;       // batch rows per WG  (grid = 256 = 1 WG/CU)
constexpr int AP = 72;      // Abuf row pitch in bf16 elems (144 B, 16B-aligned slices)
constexpr int T6 = T_ * I_;

__global__ __launch_bounds__(256, 1)
void lstm_kernel(const float* __restrict__ x,
                 const float* __restrict__ W_ih, const float* __restrict__ W_hh,
                 const float* __restrict__ b_ih, const float* __restrict__ b_hh,
                 const float* __restrict__ W_out, const float* __restrict__ b_out,
                 float* __restrict__ out)
{
  __shared__ unsigned short Xpack[T_][NB][8];  // 64 KB: [x0..x5, 1.0, 0] bf16 per (t,b)
  __shared__ unsigned short Abuf[2][NB * AP];  // 2.25 KB: h rows, elems 50..71 stay 0
  __shared__ float Hlast[NB][H_];

  const int tid  = threadIdx.x;
  const int lane = tid & 63;
  const int wave = tid >> 6;     // 0..3
  const int col  = lane & 15;    // MFMA N index
  const int quad = lane >> 4;    // MFMA k-slice group
  const int bb   = col & 7;      // batch row (broadcast pairs)
  const bool lo  = col < 8;
  const int b0   = blockIdx.x * NB;

  // ---- stage Xpack: thread handles t = tid, tid+256; coalesced 24B reads ----
  for (int tt = tid; tt < T_; tt += 256) {
    #pragma unroll
    for (int i = 0; i < NB; i++) {
      const float* xp = x + (size_t)(b0 + i) * T6 + tt * I_;
      const float2 a0 = *(const float2*)(xp);
      const float2 a1 = *(const float2*)(xp + 2);
      const float2 a2 = *(const float2*)(xp + 4);
      unsigned* dst = (unsigned*)&Xpack[tt][i][0];
      dst[0] = (unsigned)f2bf(a0.x) | ((unsigned)f2bf(a0.y) << 16);
      dst[1] = (unsigned)f2bf(a1.x) | ((unsigned)f2bf(a1.y) << 16);
      dst[2] = (unsigned)f2bf(a2.x) | ((unsigned)f2bf(a2.y) << 16);
      dst[3] = 0x3F80u;            // [bias=1.0, 0]
    }
  }
  for (int i = tid; i < 2 * NB * AP; i += 256) (&Abuf[0][0])[i] = 0;

  // ---- weight fragments, pre-scaled. Wave w: tiles jt = w + 4*ti, ti=0..3.
  // jt >= 13 -> jp >= 208 -> zero tiles (uniform 4-tile loop, balanced).
  // wfh: k' 0..49 = W_hh row (k'>=50 zero). wfx: quad0 k 0..7 = [W_ih|bias|0].
  s16x8 wfh[4][2], wfx[4];
  #pragma unroll
  for (int ti = 0; ti < 4; ti++) {
    const int jp = (wave + 4 * ti) * 16 + col;
    const bool ok = jp < 200;
    const int hidx = jp >> 2, gat = jp & 3;
    const int row = gat * 50 + hidx;
    const float scl = (gat == 2) ? (2.0f * L2E) : L2E;
    #pragma unroll
    for (int kh = 0; kh < 2; kh++) {
      s16x8 w;
      #pragma unroll
      for (int kk = 0; kk < 8; kk++) {
        const int k = kh * 32 + quad * 8 + kk;
        const float v = (ok && k < 50) ? W_hh[row * 50 + k] : 0.0f;
        w[kk] = (short)f2bf(v * scl);
      }
      wfh[ti][kh] = w;
    }
    s16x8 wx;
    #pragma unroll
    for (int kk = 0; kk < 8; kk++) {
      float v = 0.0f;
      if (ok && quad == 0) {
        if      (kk < 6)  v = W_ih[row * 6 + kk];
        else if (kk == 6) v = b_ih[row] + b_hh[row];
      }
      wx[kk] = (short)f2bf(v * scl);
    }
    wfx[ti] = wx;
  }

  // ---- lane pair identity: pair0 tile = wave + 4*(col>=8), pair1 = +8 ----
  const int hh0 = 4 * (wave + 4 * (lo ? 0 : 1)) + quad;   // 0..31
  const int hh1 = hh0 + 32;                               // 32..63 (some invalid)
  const bool valid1 = lo || (wave == 0 && quad < 2);      // hh1 < 50 && tile exists

  float c0 = 0.f, c1 = 0.f, h0r = 0.f, h1r = 0.f;
  const f32x4 zz = {0.f, 0.f, 0.f, 0.f};

  __syncthreads();

  // prologue: x-part for t=0
  f32x4 accx[4];
  {
    const s16x8 bx = *(const s16x8*)&Xpack[0][bb][0];
    #pragma unroll
    for (int ti = 0; ti < 4; ti++)
      accx[ti] = __builtin_amdgcn_mfma_f32_16x16x32_bf16(wfx[ti], bx, zz, 0, 0, 0);
  }

  #pragma unroll 2
  for (int t = 0; t < T_; t++) {
    const unsigned short* Ar = &Abuf[t & 1][0];
    unsigned short*       Aw = &Abuf[(t + 1) & 1][0];

    // h-dependent B-frags, broadcast row (col&7): conflict-free b128 reads
    const unsigned short* arow = Ar + bb * AP;
    const s16x8 bfr0 = *(const s16x8*)(arow + quad * 8);        // k' 0..31
    const s16x8 bfr1 = *(const s16x8*)(arow + 32 + quad * 8);   // k' 32..63

    f32x4 a[4];
    #pragma unroll
    for (int ti = 0; ti < 4; ti++) {
      a[ti] = __builtin_amdgcn_mfma_f32_16x16x32_bf16(wfh[ti][0], bfr0, accx[ti], 0, 0, 0);
      a[ti] = __builtin_amdgcn_mfma_f32_16x16x32_bf16(wfh[ti][1], bfr1, a[ti],    0, 0, 0);
    }

    // off-chain: x-part for step t+1 (h-independent)
    {
      const s16x8 bx = *(const s16x8*)&Xpack[(t + 1) & (T_ - 1)][bb][0];
      #pragma unroll
      for (int ti = 0; ti < 4; ti++)
        accx[ti] = __builtin_amdgcn_mfma_f32_16x16x32_bf16(wfx[ti], bx, zz, 0, 0, 0);
    }

    // broadcast-B select: every lane holds its (bb, hh) quad in acc already
    f32x4 g0, g1;
    #pragma unroll
    for (int r = 0; r < 4; r++) {
      g0[r] = lo ? a[0][r] : a[1][r];
      g1[r] = lo ? a[2][r] : a[3][r];
    }

    h0r = lstm_cell(g0, c0);
    h1r = lstm_cell(g1, c1);

    Aw[bb * AP + hh0] = f2bf(h0r);
    if (valid1) Aw[bb * AP + hh1] = f2bf(h1r);

    __syncthreads();  // h visible to all waves; lgkm-only drain (no vmcnt)
  }

  // ---- epilogue: logits + softmax ----
  Hlast[bb][hh0] = h0r;
  if (valid1) Hlast[bb][hh1] = h1r;
  __syncthreads();

  if (tid < NB) {
    float l[3];
    #pragma unroll
    for (int o = 0; o < 3; o++) {
      float s = b_out[o];
      for (int k = 0; k < H_; k++) s += W_out[o * H_ + k] * Hlast[tid][k];
      l[o] = s;
    }
    const float m  = fmaxf(l[0], fmaxf(l[1], l[2]));
    const float e0 = fast_exp2((l[0] - m) * L2E);
    const float e1 = fast_exp2((l[1] - m) * L2E);
    const float e2 = fast_exp2((l[2] - m) * L2E);
    const float inv = fast_rcp(e0 + e1 + e2);
    float* op = out + (size_t)(b0 + tid) * 3;
    op[0] = e0 * inv; op[1] = e1 * inv; op[2] = e2 * inv;
  }
}

extern "C" void kernel_launch(void* const* d_in, const int* in_sizes, int n_in,
                              void* d_out, int out_size, void* d_ws, size_t ws_size,
                              hipStream_t stream) {
  const float* x     = (const float*)d_in[0];
  const float* W_ih  = (const float*)d_in[1];
  const float* W_hh  = (const float*)d_in[2];
  const float* b_ih  = (const float*)d_in[3];
  const float* b_hh  = (const float*)d_in[4];
  const float* W_out = (const float*)d_in[5];
  const float* b_out = (const float*)d_in[6];
  lstm_kernel<<<B_ / NB, 256, 0, stream>>>(x, W_ih, W_hh, b_ih, b_hh,
                                           W_out, b_out, (float*)d_out);
}

// Round 4
// 257.179 us; speedup vs baseline: 1.0087x; 1.0087x over previous
//
#include <hip/hip_runtime.h>

// LSTM: B=2048, T=512, I=6, H=50, O=3. fp32 in/out, bf16 MFMA inner matmul.
//
// R7: R6's short chain + restored latency hiding via ANTI-PHASE workgroups.
// R6 (1 wave/SIMD, barrier-locked) exposed ~300cy/step of raw latency
// (cell transcendental chain, LDS read, MFMA dep). Fix: NB=4, grid=512,
// 256 thr -> 2 co-resident WGs/CU with INDEPENDENT barriers: when WG A is
// in its barrier/lgkm drain, WG B issues. Per-lane work halves (1 cell,
// pairs = 4b x 50hh = 200 over 256 lanes) so per-SIMD issue/step is ~R6;
// the exposed latency is what the partner WG covers.
//
// Carried from R6: broadcast-B (bb = col&3; batch cols duplicated 4x ->
// every lane holds a valid (b,hh) gate quad for EVERY tile; acc select =
// 12 cndmask, no shfl/LDS; b128 reads same-addr broadcast = conflict-free),
// x-part off-chain (accx = mfma(wfx, Xpack[t+1]) is next step's C-input),
// fused cell (8 transcendentals: sig(i)*tanh(g) = (eg-1)*rcp((1+ei)(1+eg))),
// weights pre-scaled by L2E / 2*L2E. 1 barrier/step, lgkm-only drain.

#define L2E 1.44269504088896340736f

typedef float  f32x4 __attribute__((ext_vector_type(4)));
typedef short  s16x8 __attribute__((ext_vector_type(8)));   // 8 bf16 bit-patterns

__device__ __forceinline__ float fast_exp2(float x){ return __builtin_amdgcn_exp2f(x); }
__device__ __forceinline__ float fast_rcp (float x){ return __builtin_amdgcn_rcpf(x); }

// float -> bf16 bits, round-to-nearest-even
__device__ __forceinline__ unsigned short f2bf(float f){
  unsigned u = __builtin_bit_cast(unsigned, f);
  u = (u + 0x7FFFu + ((u >> 16) & 1u)) >> 16;
  return (unsigned short)u;
}

// gates pre-scaled: g[0,1,3] = L2E*(i,f,o), g[2] = 2*L2E*g. Updates c,
// returns h. 8 transcendentals (5 exp2 + 3 rcp).
__device__ __forceinline__ float lstm_cell(const f32x4 g, float& c){
  const float ef = fast_exp2(-g[1]);
  const float sf = fast_rcp(1.0f + ef);                    // sigmoid(f)
  const float yg = fminf(fmaxf(g[2], -115.f), 115.f);
  const float eg = fast_exp2(yg);
  const float ei = fast_exp2(-g[0]);
  const float r1 = fast_rcp((1.0f + ei) * (1.0f + eg));
  c = sf * c + (eg - 1.0f) * r1;                           // f*c + sig(i)*tanh(g)
  const float yc = fminf(fmaxf(c * (2.0f * L2E), -115.f), 115.f);
  const float ec = fast_exp2(yc);
  const float eo = fast_exp2(-g[3]);
  const float r2 = fast_rcp((1.0f + eo) * (1.0f + ec));
  return (ec - 1.0f) * r2;                                 // sig(o)*tanh(c)
}

constexpr int B_ = 2048, T_ = 512, I_ = 6, H_ = 50;
constexpr int NB = 4;       // batch rows per WG  (grid = 512 = 2 WGs/CU)
constexpr int AP = 72;      // Abuf row pitch in bf16 elems (144 B, 16B-aligned slices)
constexpr int T6 = T_ * I_;

__global__ __launch_bounds__(256, 2)
void lstm_kernel(const float* __restrict__ x,
                 const float* __restrict__ W_ih, const float* __restrict__ W_hh,
                 const float* __restrict__ b_ih, const float* __restrict__ b_hh,
                 const float* __restrict__ W_out, const float* __restrict__ b_out,
                 float* __restrict__ out)
{
  __shared__ unsigned short Xpack[T_][NB][8];  // 32 KB: [x0..x5, 1.0, 0] bf16 per (t,b)
  __shared__ unsigned short Abuf[2][NB * AP];  // 1.1 KB: h rows, elems 50..71 stay 0
  __shared__ float Hlast[NB][H_];

  const int tid  = threadIdx.x;
  const int lane = tid & 63;
  const int wave = tid >> 6;     // 0..3
  const int col  = lane & 15;    // MFMA N index
  const int quad = lane >> 4;    // MFMA k-slice group
  const int bb   = col & 3;      // batch row (4-way broadcast)
  const int sel  = col >> 2;     // which tile this lane's pair comes from
  const int b0   = blockIdx.x * NB;

  // ---- stage Xpack: thread handles t = tid, tid+256; coalesced 24B reads ----
  for (int tt = tid; tt < T_; tt += 256) {
    #pragma unroll
    for (int i = 0; i < NB; i++) {
      const float* xp = x + (size_t)(b0 + i) * T6 + tt * I_;
      const float2 a0 = *(const float2*)(xp);
      const float2 a1 = *(const float2*)(xp + 2);
      const float2 a2 = *(const float2*)(xp + 4);
      unsigned* dst = (unsigned*)&Xpack[tt][i][0];
      dst[0] = (unsigned)f2bf(a0.x) | ((unsigned)f2bf(a0.y) << 16);
      dst[1] = (unsigned)f2bf(a1.x) | ((unsigned)f2bf(a1.y) << 16);
      dst[2] = (unsigned)f2bf(a2.x) | ((unsigned)f2bf(a2.y) << 16);
      dst[3] = 0x3F80u;            // [bias=1.0, 0]
    }
  }
  for (int i = tid; i < 2 * NB * AP; i += 256) (&Abuf[0][0])[i] = 0;

  // ---- weight fragments, pre-scaled. Wave w: tiles jt = w + 4*ti, ti=0..3.
  // jt >= 13 -> jp >= 208 -> zero tiles (uniform 4-tile loop, balanced).
  // wfh: k' 0..49 = W_hh row (k'>=50 zero). wfx: quad0 k 0..7 = [W_ih|bias|0].
  s16x8 wfh[4][2], wfx[4];
  #pragma unroll
  for (int ti = 0; ti < 4; ti++) {
    const int jp = (wave + 4 * ti) * 16 + col;
    const bool ok = jp < 200;
    const int hidx = jp >> 2, gat = jp & 3;
    const int row = gat * 50 + hidx;
    const float scl = (gat == 2) ? (2.0f * L2E) : L2E;
    #pragma unroll
    for (int kh = 0; kh < 2; kh++) {
      s16x8 w;
      #pragma unroll
      for (int kk = 0; kk < 8; kk++) {
        const int k = kh * 32 + quad * 8 + kk;
        const float v = (ok && k < 50) ? W_hh[row * 50 + k] : 0.0f;
        w[kk] = (short)f2bf(v * scl);
      }
      wfh[ti][kh] = w;
    }
    s16x8 wx;
    #pragma unroll
    for (int kk = 0; kk < 8; kk++) {
      float v = 0.0f;
      if (ok && quad == 0) {
        if      (kk < 6)  v = W_ih[row * 6 + kk];
        else if (kk == 6) v = b_ih[row] + b_hh[row];
      }
      wx[kk] = (short)f2bf(v * scl);
    }
    wfx[ti] = wx;
  }

  // ---- lane pair identity: tile jt = wave + 4*sel, hh = 4*jt + quad ----
  const int jt_r = wave + 4 * sel;
  const int hh   = 4 * jt_r + quad;
  const bool valid = (jt_r < 13) && (hh < H_);

  float c_ = 0.f, hreg = 0.f;
  const f32x4 zz = {0.f, 0.f, 0.f, 0.f};

  __syncthreads();

  // prologue: x-part for t=0
  f32x4 accx[4];
  {
    const s16x8 bx = *(const s16x8*)&Xpack[0][bb][0];
    #pragma unroll
    for (int ti = 0; ti < 4; ti++)
      accx[ti] = __builtin_amdgcn_mfma_f32_16x16x32_bf16(wfx[ti], bx, zz, 0, 0, 0);
  }

  #pragma unroll 2
  for (int t = 0; t < T_; t++) {
    const unsigned short* Ar = &Abuf[t & 1][0];
    unsigned short*       Aw = &Abuf[(t + 1) & 1][0];

    // h-dependent B-frags, broadcast row (col&3): conflict-free b128 reads
    const unsigned short* arow = Ar + bb * AP;
    const s16x8 bfr0 = *(const s16x8*)(arow + quad * 8);        // k' 0..31
    const s16x8 bfr1 = *(const s16x8*)(arow + 32 + quad * 8);   // k' 32..63

    f32x4 a[4];
    #pragma unroll
    for (int ti = 0; ti < 4; ti++) {
      a[ti] = __builtin_amdgcn_mfma_f32_16x16x32_bf16(wfh[ti][0], bfr0, accx[ti], 0, 0, 0);
      a[ti] = __builtin_amdgcn_mfma_f32_16x16x32_bf16(wfh[ti][1], bfr1, a[ti],    0, 0, 0);
    }

    // off-chain: x-part for step t+1 (h-independent)
    {
      const s16x8 bx = *(const s16x8*)&Xpack[(t + 1) & (T_ - 1)][bb][0];
      #pragma unroll
      for (int ti = 0; ti < 4; ti++)
        accx[ti] = __builtin_amdgcn_mfma_f32_16x16x32_bf16(wfx[ti], bx, zz, 0, 0, 0);
    }

    // 1-of-4 tile select: every lane already holds its (bb, hh) quad
    f32x4 g;
    #pragma unroll
    for (int r = 0; r < 4; r++) {
      const float lo = (sel & 1) ? a[1][r] : a[0][r];
      const float hi = (sel & 1) ? a[3][r] : a[2][r];
      g[r] = (sel & 2) ? hi : lo;
    }

    hreg = lstm_cell(g, c_);
    if (valid) Aw[bb * AP + hh] = f2bf(hreg);

    __syncthreads();  // h visible to all waves; lgkm-only drain (no vmcnt)
  }

  // ---- epilogue: logits + softmax ----
  if (valid) Hlast[bb][hh] = hreg;
  __syncthreads();

  if (tid < NB) {
    float l[3];
    #pragma unroll
    for (int o = 0; o < 3; o++) {
      float s = b_out[o];
      for (int k = 0; k < H_; k++) s += W_out[o * H_ + k] * Hlast[tid][k];
      l[o] = s;
    }
    const float m  = fmaxf(l[0], fmaxf(l[1], l[2]));
    const float e0 = fast_exp2((l[0] - m) * L2E);
    const float e1 = fast_exp2((l[1] - m) * L2E);
    const float e2 = fast_exp2((l[2] - m) * L2E);
    const float inv = fast_rcp(e0 + e1 + e2);
    float* op = out + (size_t)(b0 + tid) * 3;
    op[0] = e0 * inv; op[1] = e1 * inv; op[2] = e2 * inv;
  }
}

extern "C" void kernel_launch(void* const* d_in, const int* in_sizes, int n_in,
                              void* d_out, int out_size, void* d_ws, size_t ws_size,
                              hipStream_t stream) {
  const float* x     = (const float*)d_in[0];
  const float* W_ih  = (const float*)d_in[1];
  const float* W_hh  = (const float*)d_in[2];
  const float* b_ih  = (const float*)d_in[3];
  const float* b_hh  = (const float*)d_in[4];
  const float* W_out = (const float*)d_in[5];
  const float* b_out = (const float*)d_in[6];
  lstm_kernel<<<B_ / NB, 256, 0, stream>>>(x, W_ih, W_hh, b_ih, b_hh,
                                           W_out, b_out, (float*)d_out);
}

// Round 5
// 232.654 us; speedup vs baseline: 1.1151x; 1.1054x over previous
//
#include <hip/hip_runtime.h>

// LSTM: B=2048, T=512, I=6, H=50, O=3. fp32 in/out, bf16 MFMA inner matmul.
//
// R8: R5's wave structure (the measured best: NB=8, 512 thr, 8 waves,
// 1 WG/CU, 2 waves/SIMD same-WG) + R7's measured per-step chain cuts:
//  - Broadcast-B: bb = col&7 -> batch cols duplicated into cols 8..15;
//    every lane holds a valid (b,hh) gate quad for BOTH of its wave's
//    tiles. Redistribution = 4 cndmask (no shfl_xor, no LDS round-trip);
//    Abuf b128 reads become same-addr-broadcast conflict-free.
//  - x-part off-chain: accx[ti] = mfma(wfx[ti], Xpack[t+1]) issued during
//    step t (h-independent), is the C-input of step t+1's h-MFMAs.
//    k' 0..49 = pure h; x/bias live in accx's own k-space.
//  - Fused cell: sig(i)*tanh(g) = (eg-1)*rcp((1+ei)(1+eg)) -> 8
//    transcendentals/cell (5 exp2 + 3 rcp), clamps keep NaN out.
//  - NEW: XOR-swizzled Xpack (i*8 ^ ((t&7)<<3) shorts): staging writes
//    were lane-stride-128B = same-bank 64-way (the residual 2.5e6
//    conflicts in R6/R7); swizzle spreads 8 ways. Reads stay broadcast.
// Wave w owns tiles {w, w+8} (w>=5: 2nd tile zero-padded -> uniform).
// Lane pair: b = col&7, hh = 4*(wave + 8*(col>=8)) + quad.
// 1 barrier/step, lgkm-only drain; c-state in registers; weights
// pre-scaled by L2E (sigmoid rows) / 2*L2E (tanh rows).

#define L2E 1.44269504088896340736f

typedef float  f32x4 __attribute__((ext_vector_type(4)));
typedef short  s16x8 __attribute__((ext_vector_type(8)));   // 8 bf16 bit-patterns

__device__ __forceinline__ float fast_exp2(float x){ return __builtin_amdgcn_exp2f(x); }
__device__ __forceinline__ float fast_rcp (float x){ return __builtin_amdgcn_rcpf(x); }

// float -> bf16 bits, round-to-nearest-even
__device__ __forceinline__ unsigned short f2bf(float f){
  unsigned u = __builtin_bit_cast(unsigned, f);
  u = (u + 0x7FFFu + ((u >> 16) & 1u)) >> 16;
  return (unsigned short)u;
}

// gates pre-scaled: g[0,1,3] = L2E*(i,f,o), g[2] = 2*L2E*g. Updates c,
// returns h. 8 transcendentals (5 exp2 + 3 rcp).
__device__ __forceinline__ float lstm_cell(const f32x4 g, float& c){
  const float ef = fast_exp2(-g[1]);
  const float sf = fast_rcp(1.0f + ef);                    // sigmoid(f)
  const float yg = fminf(fmaxf(g[2], -115.f), 115.f);
  const float eg = fast_exp2(yg);
  const float ei = fast_exp2(-g[0]);
  const float r1 = fast_rcp((1.0f + ei) * (1.0f + eg));
  c = sf * c + (eg - 1.0f) * r1;                           // f*c + sig(i)*tanh(g)
  const float yc = fminf(fmaxf(c * (2.0f * L2E), -115.f), 115.f);
  const float ec = fast_exp2(yc);
  const float eo = fast_exp2(-g[3]);
  const float r2 = fast_rcp((1.0f + eo) * (1.0f + ec));
  return (ec - 1.0f) * r2;                                 // sig(o)*tanh(c)
}

constexpr int B_ = 2048, T_ = 512, I_ = 6, H_ = 50;
constexpr int NB = 8;       // batch rows per WG  (grid = 256 = 1 WG/CU)
constexpr int AP = 72;      // Abuf row pitch in bf16 elems (144 B)
constexpr int T6 = T_ * I_;

__global__ __launch_bounds__(512, 1)
void lstm_kernel(const float* __restrict__ x,
                 const float* __restrict__ W_ih, const float* __restrict__ W_hh,
                 const float* __restrict__ b_ih, const float* __restrict__ b_hh,
                 const float* __restrict__ W_out, const float* __restrict__ b_out,
                 float* __restrict__ out)
{
  // Xpack flat, XOR-swizzled: (t,b) slot = t*64 + (b*8 ^ ((t&7)<<3)) shorts.
  __shared__ unsigned short Xpack[T_ * NB * 8]; // 64 KB: [x0..x5, 1.0, 0] bf16
  __shared__ unsigned short Abuf[2][NB * AP];   // 2.25 KB: h at 0..49, rest 0
  __shared__ float Hlast[NB][H_];

  const int tid  = threadIdx.x;
  const int lane = tid & 63;
  const int wave = tid >> 6;     // 0..7
  const int col  = lane & 15;    // MFMA N index
  const int quad = lane >> 4;    // MFMA k-slice group
  const int bb   = col & 7;      // batch row (2-way broadcast)
  const bool lo  = col < 8;      // tile select: lo -> tile wave, hi -> wave+8
  const int b0   = blockIdx.x * NB;

  // ---- stage Xpack: thread tid handles t = tid (coalesced 24B reads) ----
  {
    const int tt = tid;          // 512 threads = 512 timesteps
    const int swz = (tt & 7) << 3;
    #pragma unroll
    for (int i = 0; i < NB; i++) {
      const float* xp = x + (size_t)(b0 + i) * T6 + tt * I_;
      const float2 a0 = *(const float2*)(xp);
      const float2 a1 = *(const float2*)(xp + 2);
      const float2 a2 = *(const float2*)(xp + 4);
      s16x8 w;
      w[0] = (short)f2bf(a0.x); w[1] = (short)f2bf(a0.y);
      w[2] = (short)f2bf(a1.x); w[3] = (short)f2bf(a1.y);
      w[4] = (short)f2bf(a2.x); w[5] = (short)f2bf(a2.y);
      w[6] = (short)0x3F80;     w[7] = 0;           // [bias=1.0, 0]
      *(s16x8*)&Xpack[tt * 64 + (i * 8 ^ swz)] = w;
    }
  }
  for (int i = tid; i < 2 * NB * AP; i += 512) (&Abuf[0][0])[i] = 0;

  // ---- weight fragments, pre-scaled. Wave w: tiles jt = w + 8*ti, ti=0..1.
  // jt >= 13 -> jp >= 208 -> zero tiles (uniform 2-tile loop, balanced).
  // wfh: k' 0..49 = W_hh row (k'>=50 zero). wfx: quad0 k 0..7 = [W_ih|bias|0].
  s16x8 wfh[2][2], wfx[2];
  #pragma unroll
  for (int ti = 0; ti < 2; ti++) {
    const int jp = (wave + 8 * ti) * 16 + col;
    const bool ok = jp < 200;
    const int hidx = jp >> 2, gat = jp & 3;
    const int row = gat * 50 + hidx;
    const float scl = (gat == 2) ? (2.0f * L2E) : L2E;
    #pragma unroll
    for (int kh = 0; kh < 2; kh++) {
      s16x8 w;
      #pragma unroll
      for (int kk = 0; kk < 8; kk++) {
        const int k = kh * 32 + quad * 8 + kk;
        const float v = (ok && k < 50) ? W_hh[row * 50 + k] : 0.0f;
        w[kk] = (short)f2bf(v * scl);
      }
      wfh[ti][kh] = w;
    }
    s16x8 wx;
    #pragma unroll
    for (int kk = 0; kk < 8; kk++) {
      float v = 0.0f;
      if (ok && quad == 0) {
        if      (kk < 6)  v = W_ih[row * 6 + kk];
        else if (kk == 6) v = b_ih[row] + b_hh[row];
      }
      wx[kk] = (short)f2bf(v * scl);
    }
    wfx[ti] = wx;
  }

  // ---- lane pair identity: tile jt = wave + 8*(col>=8), hh = 4*jt + quad ----
  const int jt_r = wave + 8 * (lo ? 0 : 1);
  const int hh   = 4 * jt_r + quad;
  const bool valid = (jt_r < 13) && (hh < H_);

  float c_ = 0.f, hreg = 0.f;
  const f32x4 zz = {0.f, 0.f, 0.f, 0.f};

  __syncthreads();

  // prologue: x-part for t=0 (swz = 0 at t=0)
  f32x4 accx[2];
  {
    const s16x8 bx = *(const s16x8*)&Xpack[bb * 8];
    #pragma unroll
    for (int ti = 0; ti < 2; ti++)
      accx[ti] = __builtin_amdgcn_mfma_f32_16x16x32_bf16(wfx[ti], bx, zz, 0, 0, 0);
  }

  #pragma unroll 2
  for (int t = 0; t < T_; t++) {
    const unsigned short* Ar = &Abuf[t & 1][0];
    unsigned short*       Aw = &Abuf[(t + 1) & 1][0];

    // h-dependent B-frags, broadcast row (col&7): conflict-free b128 reads
    const unsigned short* arow = Ar + bb * AP;
    const s16x8 bfr0 = *(const s16x8*)(arow + quad * 8);        // k' 0..31
    const s16x8 bfr1 = *(const s16x8*)(arow + 32 + quad * 8);   // k' 32..63

    f32x4 a[2];
    #pragma unroll
    for (int ti = 0; ti < 2; ti++) {
      a[ti] = __builtin_amdgcn_mfma_f32_16x16x32_bf16(wfh[ti][0], bfr0, accx[ti], 0, 0, 0);
      a[ti] = __builtin_amdgcn_mfma_f32_16x16x32_bf16(wfh[ti][1], bfr1, a[ti],    0, 0, 0);
    }

    // off-chain: x-part for step t+1 (h-independent, fills MFMA latency gap)
    {
      const int tn = (t + 1) & (T_ - 1);
      const s16x8 bx = *(const s16x8*)&Xpack[tn * 64 + (bb * 8 ^ ((tn & 7) << 3))];
      #pragma unroll
      for (int ti = 0; ti < 2; ti++)
        accx[ti] = __builtin_amdgcn_mfma_f32_16x16x32_bf16(wfx[ti], bx, zz, 0, 0, 0);
    }

    // tile select: every lane already holds its (bb, hh) quad
    f32x4 g;
    #pragma unroll
    for (int r = 0; r < 4; r++) g[r] = lo ? a[0][r] : a[1][r];

    hreg = lstm_cell(g, c_);
    if (valid) Aw[bb * AP + hh] = f2bf(hreg);

    __syncthreads();  // h visible to all waves; lgkm-only drain (no vmcnt)
  }

  // ---- epilogue: logits + softmax ----
  if (valid) Hlast[bb][hh] = hreg;
  __syncthreads();

  if (tid < NB) {
    float l[3];
    #pragma unroll
    for (int o = 0; o < 3; o++) {
      float s = b_out[o];
      for (int k = 0; k < H_; k++) s += W_out[o * H_ + k] * Hlast[tid][k];
      l[o] = s;
    }
    const float m  = fmaxf(l[0], fmaxf(l[1], l[2]));
    const float e0 = fast_exp2((l[0] - m) * L2E);
    const float e1 = fast_exp2((l[1] - m) * L2E);
    const float e2 = fast_exp2((l[2] - m) * L2E);
    const float inv = fast_rcp(e0 + e1 + e2);
    float* op = out + (size_t)(b0 + tid) * 3;
    op[0] = e0 * inv; op[1] = e1 * inv; op[2] = e2 * inv;
  }
}

extern "C" void kernel_launch(void* const* d_in, const int* in_sizes, int n_in,
                              void* d_out, int out_size, void* d_ws, size_t ws_size,
                              hipStream_t stream) {
  const float* x     = (const float*)d_in[0];
  const float* W_ih  = (const float*)d_in[1];
  const float* W_hh  = (const float*)d_in[2];
  const float* b_ih  = (const float*)d_in[3];
  const float* b_hh  = (const float*)d_in[4];
  const float* W_out = (const float*)d_in[5];
  const float* b_out = (const float*)d_in[6];
  lstm_kernel<<<B_ / NB, 512, 0, stream>>>(x, W_ih, W_hh, b_ih, b_hh,
                                           W_out, b_out, (float*)d_out);
}

// Round 6
// 218.730 us; speedup vs baseline: 1.1860x; 1.0637x over previous
//
#include <hip/hip_runtime.h>

// LSTM: B=2048, T=512, I=6, H=50, O=3. fp32 in/out, bf16 MFMA inner matmul.
//
// R9 = R8 (best: NB=8, 512 thr, 8 waves, 1 WG/CU) + two chain/conflict cuts:
//  - AP 72 -> 88 shorts (176 B): Abuf b128 read start-bank becomes
//    (12*bb + 4*quad) mod 32; 12*bb mod 32 = {0,12,24,4,16,28,8,20} ->
//    all 8 bb rows in distinct bank quartets, <=2-way any phasing (free).
//    At AP=72 it was 4*(bb+quad) mod 32 -> 4-way groups = the 9.5e6
//    conflicts (73 cyc/WG/step) measured in R8.
//  - x-feed register prefetch ACROSS the barrier: bx(t+1) is ds_read into
//    registers during step t's cell phase; step t+1's two x-MFMAs then have
//    register-ready operands and execute immediately post-barrier, under
//    the ~120cy bfr ds_read shadow (h-MFMAs wait on lgkm after them).
// Carried: broadcast-B (bb=col&7, tile select = 4 cndmask, no shfl),
// accx as C-input of h-MFMAs, fused 8-transcendental cell, weights
// pre-scaled by L2E / 2*L2E, XOR-swizzled Xpack staging, 1 barrier/step.
// Wave w owns tiles {w, w+8}; lane pair: b=col&7, hh=4*(wave+8*(col>=8))+quad.

#define L2E 1.44269504088896340736f

typedef float  f32x4 __attribute__((ext_vector_type(4)));
typedef short  s16x8 __attribute__((ext_vector_type(8)));   // 8 bf16 bit-patterns

__device__ __forceinline__ float fast_exp2(float x){ return __builtin_amdgcn_exp2f(x); }
__device__ __forceinline__ float fast_rcp (float x){ return __builtin_amdgcn_rcpf(x); }

// float -> bf16 bits, round-to-nearest-even
__device__ __forceinline__ unsigned short f2bf(float f){
  unsigned u = __builtin_bit_cast(unsigned, f);
  u = (u + 0x7FFFu + ((u >> 16) & 1u)) >> 16;
  return (unsigned short)u;
}

// gates pre-scaled: g[0,1,3] = L2E*(i,f,o), g[2] = 2*L2E*g. Updates c,
// returns h. 8 transcendentals (5 exp2 + 3 rcp).
__device__ __forceinline__ float lstm_cell(const f32x4 g, float& c){
  const float ef = fast_exp2(-g[1]);
  const float sf = fast_rcp(1.0f + ef);                    // sigmoid(f)
  const float yg = fminf(fmaxf(g[2], -115.f), 115.f);
  const float eg = fast_exp2(yg);
  const float ei = fast_exp2(-g[0]);
  const float r1 = fast_rcp((1.0f + ei) * (1.0f + eg));
  c = sf * c + (eg - 1.0f) * r1;                           // f*c + sig(i)*tanh(g)
  const float yc = fminf(fmaxf(c * (2.0f * L2E), -115.f), 115.f);
  const float ec = fast_exp2(yc);
  const float eo = fast_exp2(-g[3]);
  const float r2 = fast_rcp((1.0f + eo) * (1.0f + ec));
  return (ec - 1.0f) * r2;                                 // sig(o)*tanh(c)
}

constexpr int B_ = 2048, T_ = 512, I_ = 6, H_ = 50;
constexpr int NB = 8;       // batch rows per WG  (grid = 256 = 1 WG/CU)
constexpr int AP = 88;      // Abuf row pitch in bf16 elems (176 B: bank-spread)
constexpr int T6 = T_ * I_;

__global__ __launch_bounds__(512, 1)
void lstm_kernel(const float* __restrict__ x,
                 const float* __restrict__ W_ih, const float* __restrict__ W_hh,
                 const float* __restrict__ b_ih, const float* __restrict__ b_hh,
                 const float* __restrict__ W_out, const float* __restrict__ b_out,
                 float* __restrict__ out)
{
  // Xpack flat, XOR-swizzled: (t,b) slot = t*64 + (b*8 ^ ((t&7)<<3)) shorts.
  __shared__ unsigned short Xpack[T_ * NB * 8]; // 64 KB: [x0..x5, 1.0, 0] bf16
  __shared__ unsigned short Abuf[2][NB * AP];   // 2.75 KB: h at 0..49, rest 0
  __shared__ float Hlast[NB][H_];

  const int tid  = threadIdx.x;
  const int lane = tid & 63;
  const int wave = tid >> 6;     // 0..7
  const int col  = lane & 15;    // MFMA N index
  const int quad = lane >> 4;    // MFMA k-slice group
  const int bb   = col & 7;      // batch row (2-way broadcast)
  const bool lo  = col < 8;      // tile select: lo -> tile wave, hi -> wave+8
  const int b0   = blockIdx.x * NB;

  // ---- stage Xpack: thread tid handles t = tid (coalesced 24B reads) ----
  {
    const int tt = tid;          // 512 threads = 512 timesteps
    const int swz = (tt & 7) << 3;
    #pragma unroll
    for (int i = 0; i < NB; i++) {
      const float* xp = x + (size_t)(b0 + i) * T6 + tt * I_;
      const float2 a0 = *(const float2*)(xp);
      const float2 a1 = *(const float2*)(xp + 2);
      const float2 a2 = *(const float2*)(xp + 4);
      s16x8 w;
      w[0] = (short)f2bf(a0.x); w[1] = (short)f2bf(a0.y);
      w[2] = (short)f2bf(a1.x); w[3] = (short)f2bf(a1.y);
      w[4] = (short)f2bf(a2.x); w[5] = (short)f2bf(a2.y);
      w[6] = (short)0x3F80;     w[7] = 0;           // [bias=1.0, 0]
      *(s16x8*)&Xpack[tt * 64 + (i * 8 ^ swz)] = w;
    }
  }
  for (int i = tid; i < 2 * NB * AP; i += 512) (&Abuf[0][0])[i] = 0;

  // ---- weight fragments, pre-scaled. Wave w: tiles jt = w + 8*ti, ti=0..1.
  // jt >= 13 -> jp >= 208 -> zero tiles (uniform 2-tile loop, balanced).
  // wfh: k' 0..49 = W_hh row (k'>=50 zero). wfx: quad0 k 0..7 = [W_ih|bias|0].
  s16x8 wfh[2][2], wfx[2];
  #pragma unroll
  for (int ti = 0; ti < 2; ti++) {
    const int jp = (wave + 8 * ti) * 16 + col;
    const bool ok = jp < 200;
    const int hidx = jp >> 2, gat = jp & 3;
    const int row = gat * 50 + hidx;
    const float scl = (gat == 2) ? (2.0f * L2E) : L2E;
    #pragma unroll
    for (int kh = 0; kh < 2; kh++) {
      s16x8 w;
      #pragma unroll
      for (int kk = 0; kk < 8; kk++) {
        const int k = kh * 32 + quad * 8 + kk;
        const float v = (ok && k < 50) ? W_hh[row * 50 + k] : 0.0f;
        w[kk] = (short)f2bf(v * scl);
      }
      wfh[ti][kh] = w;
    }
    s16x8 wx;
    #pragma unroll
    for (int kk = 0; kk < 8; kk++) {
      float v = 0.0f;
      if (ok && quad == 0) {
        if      (kk < 6)  v = W_ih[row * 6 + kk];
        else if (kk == 6) v = b_ih[row] + b_hh[row];
      }
      wx[kk] = (short)f2bf(v * scl);
    }
    wfx[ti] = wx;
  }

  // ---- lane pair identity: tile jt = wave + 8*(col>=8), hh = 4*jt + quad ----
  const int jt_r = wave + 8 * (lo ? 0 : 1);
  const int hh   = 4 * jt_r + quad;
  const bool valid = (jt_r < 13) && (hh < H_);

  float c_ = 0.f, hreg = 0.f;

  __syncthreads();

  // register-prefetch x(0) fragment (swz = 0 at t=0)
  s16x8 bx = *(const s16x8*)&Xpack[bb * 8];

  #pragma unroll 2
  for (int t = 0; t < T_; t++) {
    const unsigned short* Ar = &Abuf[t & 1][0];
    unsigned short*       Aw = &Abuf[(t + 1) & 1][0];

    // issue the h-frag ds_reads first (latency ~120cy)...
    const unsigned short* arow = Ar + bb * AP;
    const s16x8 bfr0 = *(const s16x8*)(arow + quad * 8);        // k' 0..31
    const s16x8 bfr1 = *(const s16x8*)(arow + 32 + quad * 8);   // k' 32..63

    // ...and fill their shadow with the x-MFMAs (operands already in regs,
    // prefetched across the barrier -> no lgkm dependency).
    const f32x4 zz = {0.f, 0.f, 0.f, 0.f};
    f32x4 a[2];
    #pragma unroll
    for (int ti = 0; ti < 2; ti++)
      a[ti] = __builtin_amdgcn_mfma_f32_16x16x32_bf16(wfx[ti], bx, zz, 0, 0, 0);

    // h-MFMAs (wait on bfr loads)
    #pragma unroll
    for (int ti = 0; ti < 2; ti++) {
      a[ti] = __builtin_amdgcn_mfma_f32_16x16x32_bf16(wfh[ti][0], bfr0, a[ti], 0, 0, 0);
      a[ti] = __builtin_amdgcn_mfma_f32_16x16x32_bf16(wfh[ti][1], bfr1, a[ti], 0, 0, 0);
    }

    // prefetch x(t+1) fragment into registers; completes during the cell,
    // drained (lgkm) by the end-of-step barrier, used after it.
    {
      const int tn = (t + 1) & (T_ - 1);
      bx = *(const s16x8*)&Xpack[tn * 64 + (bb * 8 ^ ((tn & 7) << 3))];
    }

    // tile select: every lane already holds its (bb, hh) quad
    f32x4 g;
    #pragma unroll
    for (int r = 0; r < 4; r++) g[r] = lo ? a[0][r] : a[1][r];

    hreg = lstm_cell(g, c_);
    if (valid) Aw[bb * AP + hh] = f2bf(hreg);

    __syncthreads();  // h visible to all waves; lgkm-only drain (no vmcnt)
  }

  // ---- epilogue: logits + softmax ----
  if (valid) Hlast[bb][hh] = hreg;
  __syncthreads();

  if (tid < NB) {
    float l[3];
    #pragma unroll
    for (int o = 0; o < 3; o++) {
      float s = b_out[o];
      for (int k = 0; k < H_; k++) s += W_out[o * H_ + k] * Hlast[tid][k];
      l[o] = s;
    }
    const float m  = fmaxf(l[0], fmaxf(l[1], l[2]));
    const float e0 = fast_exp2((l[0] - m) * L2E);
    const float e1 = fast_exp2((l[1] - m) * L2E);
    const float e2 = fast_exp2((l[2] - m) * L2E);
    const float inv = fast_rcp(e0 + e1 + e2);
    float* op = out + (size_t)(b0 + tid) * 3;
    op[0] = e0 * inv; op[1] = e1 * inv; op[2] = e2 * inv;
  }
}

extern "C" void kernel_launch(void* const* d_in, const int* in_sizes, int n_in,
                              void* d_out, int out_size, void* d_ws, size_t ws_size,
                              hipStream_t stream) {
  const float* x     = (const float*)d_in[0];
  const float* W_ih  = (const float*)d_in[1];
  const float* W_hh  = (const float*)d_in[2];
  const float* b_ih  = (const float*)d_in[3];
  const float* b_hh  = (const float*)d_in[4];
  const float* W_out = (const float*)d_in[5];
  const float* b_out = (const float*)d_in[6];
  lstm_kernel<<<B_ / NB, 512, 0, stream>>>(x, W_ih, W_hh, b_ih, b_hh,
                                           W_out, b_out, (float*)d_out);
}

// Round 7
// 213.828 us; speedup vs baseline: 1.2132x; 1.0229x over previous
//
#include <hip/hip_runtime.h>

// LSTM: B=2048, T=512, I=6, H=50, O=3. fp32 in/out, bf16 MFMA inner matmul.
//
// R10 = R9 structure + x-feed merged back into the h-MFMA K-space (R5's
// k'-map). Evidence: R8->R9's conflict counter was byte-identical despite
// the AP change -> per-step Abuf path was already conflict-free; the 9.5e6
// conflicts live in one-time Xpack staging (overlapped, harmless). The
// remaining wall is the CU-level LDS burst at barrier release: 8 waves x
// 3 b128 reads x ~12cy service = ~290 cy/step. Cut: k' 48..55 of the
// second MFMA = [x0..x5, bias, 0] read by quad-2 lanes DIRECTLY from
// Xpack (address select, no branch) -> 2 b128 reads/lane (burst ~190cy),
// 4 MFMAs/wave (was 6), no bx register prefetch.
//
// k' map: 0..47 = W_hh cols 0..47, 48..53 = W_ih (x), 54 = bias, 55 = 0,
//         56..57 = W_hh cols 48..49. h-write: pos = hh + (hh>=48 ? 8 : 0).
// Carried from R9: NB=8, 512 thr, 8 waves, 1 WG/CU; broadcast-B (bb=col&7,
// tile select = 4 cndmask); fused 8-transcendental cell; weights pre-scaled
// by L2E / 2*L2E; AP=88 (bank-spread); XOR-swizzled Xpack; 1 barrier/step,
// lgkm-only drain; c-state in registers.
// Wave w owns tiles {w, w+8}; lane pair: b=col&7, hh=4*(wave+8*(col>=8))+quad.

#define L2E 1.44269504088896340736f

typedef float  f32x4 __attribute__((ext_vector_type(4)));
typedef short  s16x8 __attribute__((ext_vector_type(8)));   // 8 bf16 bit-patterns

__device__ __forceinline__ float fast_exp2(float x){ return __builtin_amdgcn_exp2f(x); }
__device__ __forceinline__ float fast_rcp (float x){ return __builtin_amdgcn_rcpf(x); }

// float -> bf16 bits, round-to-nearest-even
__device__ __forceinline__ unsigned short f2bf(float f){
  unsigned u = __builtin_bit_cast(unsigned, f);
  u = (u + 0x7FFFu + ((u >> 16) & 1u)) >> 16;
  return (unsigned short)u;
}

// gates pre-scaled: g[0,1,3] = L2E*(i,f,o), g[2] = 2*L2E*g. Updates c,
// returns h. 8 transcendentals (5 exp2 + 3 rcp).
__device__ __forceinline__ float lstm_cell(const f32x4 g, float& c){
  const float ef = fast_exp2(-g[1]);
  const float sf = fast_rcp(1.0f + ef);                    // sigmoid(f)
  const float yg = fminf(fmaxf(g[2], -115.f), 115.f);
  const float eg = fast_exp2(yg);
  const float ei = fast_exp2(-g[0]);
  const float r1 = fast_rcp((1.0f + ei) * (1.0f + eg));
  c = sf * c + (eg - 1.0f) * r1;                           // f*c + sig(i)*tanh(g)
  const float yc = fminf(fmaxf(c * (2.0f * L2E), -115.f), 115.f);
  const float ec = fast_exp2(yc);
  const float eo = fast_exp2(-g[3]);
  const float r2 = fast_rcp((1.0f + eo) * (1.0f + ec));
  return (ec - 1.0f) * r2;                                 // sig(o)*tanh(c)
}

constexpr int B_ = 2048, T_ = 512, I_ = 6, H_ = 50;
constexpr int NB = 8;       // batch rows per WG  (grid = 256 = 1 WG/CU)
constexpr int AP = 88;      // Abuf row pitch in bf16 elems (176 B: bank-spread)
constexpr int T6 = T_ * I_;

__global__ __launch_bounds__(512, 1)
void lstm_kernel(const float* __restrict__ x,
                 const float* __restrict__ W_ih, const float* __restrict__ W_hh,
                 const float* __restrict__ b_ih, const float* __restrict__ b_hh,
                 const float* __restrict__ W_out, const float* __restrict__ b_out,
                 float* __restrict__ out)
{
  // Xpack flat, XOR-swizzled: (t,b) slot = t*64 + (b*8 ^ ((t&7)<<3)) shorts.
  // Slot content = [x0..x5, bias=1.0, 0] = k' 48..55 of the B-operand.
  __shared__ unsigned short Xpack[T_ * NB * 8]; // 64 KB
  __shared__ unsigned short Abuf[2][NB * AP];   // 2.75 KB: h at 0..47,56,57
  __shared__ float Hlast[NB][H_];

  const int tid  = threadIdx.x;
  const int lane = tid & 63;
  const int wave = tid >> 6;     // 0..7
  const int col  = lane & 15;    // MFMA N index
  const int quad = lane >> 4;    // MFMA k-slice group
  const int bb   = col & 7;      // batch row (2-way broadcast)
  const bool lo  = col < 8;      // tile select: lo -> tile wave, hi -> wave+8
  const int b0   = blockIdx.x * NB;

  // ---- stage Xpack: thread tid handles t = tid (coalesced 24B reads) ----
  {
    const int tt = tid;          // 512 threads = 512 timesteps
    const int swz = (tt & 7) << 3;
    #pragma unroll
    for (int i = 0; i < NB; i++) {
      const float* xp = x + (size_t)(b0 + i) * T6 + tt * I_;
      const float2 a0 = *(const float2*)(xp);
      const float2 a1 = *(const float2*)(xp + 2);
      const float2 a2 = *(const float2*)(xp + 4);
      s16x8 w;
      w[0] = (short)f2bf(a0.x); w[1] = (short)f2bf(a0.y);
      w[2] = (short)f2bf(a1.x); w[3] = (short)f2bf(a1.y);
      w[4] = (short)f2bf(a2.x); w[5] = (short)f2bf(a2.y);
      w[6] = (short)0x3F80;     w[7] = 0;           // [bias=1.0, 0]
      *(s16x8*)&Xpack[tt * 64 + (i * 8 ^ swz)] = w;
    }
  }
  for (int i = tid; i < 2 * NB * AP; i += 512) (&Abuf[0][0])[i] = 0;

  // ---- weight fragments, pre-scaled, R5 k'-map. Wave w: tiles jt = w + 8*ti.
  // jt >= 13 -> jp >= 208 -> zero tiles (uniform 2-tile loop, balanced).
  // k': 0..47 -> W_hh[.][k'], 48..53 -> W_ih[.][k'-48], 54 -> bias,
  //     56,57 -> W_hh[.][48,49], else 0.
  s16x8 wfh[2][2];
  #pragma unroll
  for (int ti = 0; ti < 2; ti++) {
    const int jp = (wave + 8 * ti) * 16 + col;
    const bool ok = jp < 200;
    const int hidx = jp >> 2, gat = jp & 3;
    const int row = gat * 50 + hidx;
    const float scl = (gat == 2) ? (2.0f * L2E) : L2E;
    #pragma unroll
    for (int kh = 0; kh < 2; kh++) {
      s16x8 w;
      #pragma unroll
      for (int kk = 0; kk < 8; kk++) {
        const int k = kh * 32 + quad * 8 + kk;
        float v = 0.0f;
        if (ok) {
          if      (k < 48)  v = W_hh[row * 50 + k];
          else if (k < 54)  v = W_ih[row * 6 + (k - 48)];
          else if (k == 54) v = b_ih[row] + b_hh[row];
          else if (k == 56) v = W_hh[row * 50 + 48];
          else if (k == 57) v = W_hh[row * 50 + 49];
        }
        w[kk] = (short)f2bf(v * scl);
      }
      wfh[ti][kh] = w;
    }
  }

  // ---- lane pair identity: tile jt = wave + 8*(col>=8), hh = 4*jt + quad ----
  const int jt_r = wave + 8 * (lo ? 0 : 1);
  const int hh   = 4 * jt_r + quad;
  const bool valid = (jt_r < 13) && (hh < H_);
  const int pos   = hh + ((hh >= 48) ? 8 : 0);   // h48,h49 live at 56,57

  float c_ = 0.f, hreg = 0.f;
  const f32x4 zz = {0.f, 0.f, 0.f, 0.f};

  __syncthreads();

  #pragma unroll 2
  for (int t = 0; t < T_; t++) {
    const unsigned short* Ar = &Abuf[t & 1][0];
    unsigned short*       Aw = &Abuf[(t + 1) & 1][0];

    // B-frags, broadcast row (col&7). quad2's bfr1 slice (k' 48..55) is
    // [x|bias|0], read straight from Xpack via per-lane address select.
    const unsigned short* arow = Ar + bb * AP;
    const s16x8 bfr0 = *(const s16x8*)(arow + quad * 8);        // k' 0..31
    const unsigned short* p1 = (quad == 2)
        ? &Xpack[t * 64 + (bb * 8 ^ ((t & 7) << 3))]
        : (arow + 32 + quad * 8);
    const s16x8 bfr1 = *(const s16x8*)p1;                       // k' 32..63

    // 2 MFMAs per tile (K=64 covers h + x + bias)
    f32x4 a[2];
    #pragma unroll
    for (int ti = 0; ti < 2; ti++) {
      a[ti] = __builtin_amdgcn_mfma_f32_16x16x32_bf16(wfh[ti][0], bfr0, zz,    0, 0, 0);
      a[ti] = __builtin_amdgcn_mfma_f32_16x16x32_bf16(wfh[ti][1], bfr1, a[ti], 0, 0, 0);
    }

    // tile select: every lane already holds its (bb, hh) quad
    f32x4 g;
    #pragma unroll
    for (int r = 0; r < 4; r++) g[r] = lo ? a[0][r] : a[1][r];

    hreg = lstm_cell(g, c_);
    if (valid) Aw[bb * AP + pos] = f2bf(hreg);

    __syncthreads();  // h visible to all waves; lgkm-only drain (no vmcnt)
  }

  // ---- epilogue: logits + softmax ----
  if (valid) Hlast[bb][hh] = hreg;
  __syncthreads();

  if (tid < NB) {
    float l[3];
    #pragma unroll
    for (int o = 0; o < 3; o++) {
      float s = b_out[o];
      for (int k = 0; k < H_; k++) s += W_out[o * H_ + k] * Hlast[tid][k];
      l[o] = s;
    }
    const float m  = fmaxf(l[0], fmaxf(l[1], l[2]));
    const float e0 = fast_exp2((l[0] - m) * L2E);
    const float e1 = fast_exp2((l[1] - m) * L2E);
    const float e2 = fast_exp2((l[2] - m) * L2E);
    const float inv = fast_rcp(e0 + e1 + e2);
    float* op = out + (size_t)(b0 + tid) * 3;
    op[0] = e0 * inv; op[1] = e1 * inv; op[2] = e2 * inv;
  }
}

extern "C" void kernel_launch(void* const* d_in, const int* in_sizes, int n_in,
                              void* d_out, int out_size, void* d_ws, size_t ws_size,
                              hipStream_t stream) {
  const float* x     = (const float*)d_in[0];
  const float* W_ih  = (const float*)d_in[1];
  const float* W_hh  = (const float*)d_in[2];
  const float* b_ih  = (const float*)d_in[3];
  const float* b_hh  = (const float*)d_in[4];
  const float* W_out = (const float*)d_in[5];
  const float* b_out = (const float*)d_in[6];
  lstm_kernel<<<B_ / NB, 512, 0, stream>>>(x, W_ih, W_hh, b_ih, b_hh,
                                           W_out, b_out, (float*)d_out);
}

// Round 8
// 210.446 us; speedup vs baseline: 1.2327x; 1.0161x over previous
//
#include <hip/hip_runtime.h>

// LSTM: B=2048, T=512, I=6, H=50, O=3. fp32 in/out, bf16 MFMA inner matmul.
//
// R11 = R10 + VALU/chain trims (budget: VALUBusy 52% x 737cy/step = 383cy
// VALU issue/SIMD/step is the largest cuttable term; DS-burst model was
// falsified in R10 by a null result on read-count reduction):
//  - 7-transcendental cell (was 8): sigmoid(f)'s rcp folded into the
//    tanh-term rcp: c' = (c*(1+ei)(1+eg) + (eg-1)(1+ef)) * rcp(A*B*C).
//  - g-gate clamp dropped: |g2| <= 2*L2E*0.141*(50+6*5+1) ~ 33 << 127,
//    exp2 can't overflow. c-clamp kept (c accumulates over 512 steps).
//  - f2bf via v_cvt_pk_bf16_f32 (1 instr, RNE) instead of 4-op manual.
//  - unconditional h-write: invalid lanes hit Abuf pad (pos 58..71),
//    all zero-weight k' columns, finite values -> no exec-mask dance.
//  - unroll 8: (t&7) Xpack swizzle static per slot, addresses affine.
// Carried from R10: NB=8, 512 thr, 8 waves, 1 WG/CU; R5 k'-map (x/bias in
// k'48..55 read from Xpack by quad2); broadcast-B (bb=col&7, 4-cndmask
// tile select); weights pre-scaled by L2E / 2*L2E; AP=88; XOR-swizzled
// Xpack; 1 barrier/step, lgkm-only drain; c-state in registers.

#define L2E 1.44269504088896340736f

typedef float  f32x4 __attribute__((ext_vector_type(4)));
typedef short  s16x8 __attribute__((ext_vector_type(8)));   // 8 bf16 bit-patterns

__device__ __forceinline__ float fast_exp2(float x){ return __builtin_amdgcn_exp2f(x); }
__device__ __forceinline__ float fast_rcp (float x){ return __builtin_amdgcn_rcpf(x); }

// float -> bf16 bits, round-to-nearest-even (weight staging only)
__device__ __forceinline__ unsigned short f2bf(float f){
  unsigned u = __builtin_bit_cast(unsigned, f);
  u = (u + 0x7FFFu + ((u >> 16) & 1u)) >> 16;
  return (unsigned short)u;
}

// single-instruction f32 -> bf16 (RNE) for the hot loop
__device__ __forceinline__ unsigned short f2bf_fast(float f){
  unsigned r;
  asm("v_cvt_pk_bf16_f32 %0, %1, %2" : "=v"(r) : "v"(f), "v"(0.0f));
  return (unsigned short)r;
}

// gates pre-scaled: g[0,1,3] = L2E*(i,f,o), g[2] = 2*L2E*g. Updates c,
// returns h. 7 transcendentals (5 exp2 + 2 rcp).
__device__ __forceinline__ float lstm_cell(const f32x4 g, float& c){
  const float ef = fast_exp2(-g[1]);
  const float ei = fast_exp2(-g[0]);
  const float eg = fast_exp2(g[2]);          // |g2| <= ~33: no clamp needed
  const float A  = 1.0f + ef;
  const float Bq = 1.0f + ei;
  const float Cq = 1.0f + eg;
  const float BC = Bq * Cq;
  // c' = sig(f)*c + sig(i)*tanh(g) = (c*BC + (eg-1)*A) / (A*BC)
  const float num = fmaf(eg - 1.0f, A, c * BC);
  c = num * fast_rcp(A * BC);
  const float yc = fminf(fmaxf(c * (2.0f * L2E), -115.f), 115.f);
  const float ec = fast_exp2(yc);
  const float eo = fast_exp2(-g[3]);
  const float r2 = fast_rcp((1.0f + eo) * (1.0f + ec));
  return (ec - 1.0f) * r2;                   // sig(o)*tanh(c)
}

constexpr int B_ = 2048, T_ = 512, I_ = 6, H_ = 50;
constexpr int NB = 8;       // batch rows per WG  (grid = 256 = 1 WG/CU)
constexpr int AP = 88;      // Abuf row pitch in bf16 elems (176 B: bank-spread)
constexpr int T6 = T_ * I_;

__global__ __launch_bounds__(512, 1)
void lstm_kernel(const float* __restrict__ x,
                 const float* __restrict__ W_ih, const float* __restrict__ W_hh,
                 const float* __restrict__ b_ih, const float* __restrict__ b_hh,
                 const float* __restrict__ W_out, const float* __restrict__ b_out,
                 float* __restrict__ out)
{
  // Xpack flat, XOR-swizzled: (t,b) slot = t*64 + (b*8 ^ ((t&7)<<3)) shorts.
  // Slot content = [x0..x5, bias=1.0, 0] = k' 48..55 of the B-operand.
  __shared__ unsigned short Xpack[T_ * NB * 8]; // 64 KB
  __shared__ unsigned short Abuf[2][NB * AP];   // 2.75 KB: h at 0..47,56,57
  __shared__ float Hlast[NB][H_];

  const int tid  = threadIdx.x;
  const int lane = tid & 63;
  const int wave = tid >> 6;     // 0..7
  const int col  = lane & 15;    // MFMA N index
  const int quad = lane >> 4;    // MFMA k-slice group
  const int bb   = col & 7;      // batch row (2-way broadcast)
  const bool lo  = col < 8;      // tile select: lo -> tile wave, hi -> wave+8
  const int b0   = blockIdx.x * NB;

  // ---- stage Xpack: thread tid handles t = tid (coalesced 24B reads) ----
  {
    const int tt = tid;          // 512 threads = 512 timesteps
    const int swz = (tt & 7) << 3;
    #pragma unroll
    for (int i = 0; i < NB; i++) {
      const float* xp = x + (size_t)(b0 + i) * T6 + tt * I_;
      const float2 a0 = *(const float2*)(xp);
      const float2 a1 = *(const float2*)(xp + 2);
      const float2 a2 = *(const float2*)(xp + 4);
      s16x8 w;
      w[0] = (short)f2bf(a0.x); w[1] = (short)f2bf(a0.y);
      w[2] = (short)f2bf(a1.x); w[3] = (short)f2bf(a1.y);
      w[4] = (short)f2bf(a2.x); w[5] = (short)f2bf(a2.y);
      w[6] = (short)0x3F80;     w[7] = 0;           // [bias=1.0, 0]
      *(s16x8*)&Xpack[tt * 64 + (i * 8 ^ swz)] = w;
    }
  }
  for (int i = tid; i < 2 * NB * AP; i += 512) (&Abuf[0][0])[i] = 0;

  // ---- weight fragments, pre-scaled, R5 k'-map. Wave w: tiles jt = w + 8*ti.
  // jt >= 13 -> jp >= 208 -> zero tiles (uniform 2-tile loop, balanced).
  // k': 0..47 -> W_hh[.][k'], 48..53 -> W_ih[.][k'-48], 54 -> bias,
  //     56,57 -> W_hh[.][48,49], else 0.
  s16x8 wfh[2][2];
  #pragma unroll
  for (int ti = 0; ti < 2; ti++) {
    const int jp = (wave + 8 * ti) * 16 + col;
    const bool ok = jp < 200;
    const int hidx = jp >> 2, gat = jp & 3;
    const int row = gat * 50 + hidx;
    const float scl = (gat == 2) ? (2.0f * L2E) : L2E;
    #pragma unroll
    for (int kh = 0; kh < 2; kh++) {
      s16x8 w;
      #pragma unroll
      for (int kk = 0; kk < 8; kk++) {
        const int k = kh * 32 + quad * 8 + kk;
        float v = 0.0f;
        if (ok) {
          if      (k < 48)  v = W_hh[row * 50 + k];
          else if (k < 54)  v = W_ih[row * 6 + (k - 48)];
          else if (k == 54) v = b_ih[row] + b_hh[row];
          else if (k == 56) v = W_hh[row * 50 + 48];
          else if (k == 57) v = W_hh[row * 50 + 49];
        }
        w[kk] = (short)f2bf(v * scl);
      }
      wfh[ti][kh] = w;
    }
  }

  // ---- lane pair identity: tile jt = wave + 8*(col>=8), hh = 4*jt + quad ----
  const int jt_r = wave + 8 * (lo ? 0 : 1);
  const int hh   = 4 * jt_r + quad;
  const bool valid = (jt_r < 13) && (hh < H_);
  const int pos   = hh + ((hh >= 48) ? 8 : 0);   // h48,h49 at 56,57; invalid
                                                 // lanes land in pad 58..71
                                                 // (zero-weight k' columns)

  float c_ = 0.f, hreg = 0.f;
  const f32x4 zz = {0.f, 0.f, 0.f, 0.f};

  __syncthreads();

  #pragma unroll 8
  for (int t = 0; t < T_; t++) {
    const unsigned short* Ar = &Abuf[t & 1][0];
    unsigned short*       Aw = &Abuf[(t + 1) & 1][0];

    // B-frags, broadcast row (col&7). quad2's bfr1 slice (k' 48..55) is
    // [x|bias|0], read straight from Xpack via per-lane address select.
    const unsigned short* arow = Ar + bb * AP;
    const s16x8 bfr0 = *(const s16x8*)(arow + quad * 8);        // k' 0..31
    const unsigned short* p1 = (quad == 2)
        ? &Xpack[t * 64 + (bb * 8 ^ ((t & 7) << 3))]
        : (arow + 32 + quad * 8);
    const s16x8 bfr1 = *(const s16x8*)p1;                       // k' 32..63

    // 2 MFMAs per tile (K=64 covers h + x + bias)
    f32x4 a[2];
    #pragma unroll
    for (int ti = 0; ti < 2; ti++) {
      a[ti] = __builtin_amdgcn_mfma_f32_16x16x32_bf16(wfh[ti][0], bfr0, zz,    0, 0, 0);
      a[ti] = __builtin_amdgcn_mfma_f32_16x16x32_bf16(wfh[ti][1], bfr1, a[ti], 0, 0, 0);
    }

    // tile select: every lane already holds its (bb, hh) quad
    f32x4 g;
    #pragma unroll
    for (int r = 0; r < 4; r++) g[r] = lo ? a[0][r] : a[1][r];

    hreg = lstm_cell(g, c_);
    Aw[bb * AP + pos] = f2bf_fast(hreg);   // unconditional: pad-safe

    __syncthreads();  // h visible to all waves; lgkm-only drain (no vmcnt)
  }

  // ---- epilogue: logits + softmax ----
  if (valid) Hlast[bb][hh] = hreg;
  __syncthreads();

  if (tid < NB) {
    float l[3];
    #pragma unroll
    for (int o = 0; o < 3; o++) {
      float s = b_out[o];
      for (int k = 0; k < H_; k++) s += W_out[o * H_ + k] * Hlast[tid][k];
      l[o] = s;
    }
    const float m  = fmaxf(l[0], fmaxf(l[1], l[2]));
    const float e0 = fast_exp2((l[0] - m) * L2E);
    const float e1 = fast_exp2((l[1] - m) * L2E);
    const float e2 = fast_exp2((l[2] - m) * L2E);
    const float inv = fast_rcp(e0 + e1 + e2);
    float* op = out + (size_t)(b0 + tid) * 3;
    op[0] = e0 * inv; op[1] = e1 * inv; op[2] = e2 * inv;
  }
}

extern "C" void kernel_launch(void* const* d_in, const int* in_sizes, int n_in,
                              void* d_out, int out_size, void* d_ws, size_t ws_size,
                              hipStream_t stream) {
  const float* x     = (const float*)d_in[0];
  const float* W_ih  = (const float*)d_in[1];
  const float* W_hh  = (const float*)d_in[2];
  const float* b_ih  = (const float*)d_in[3];
  const float* b_hh  = (const float*)d_in[4];
  const float* W_out = (const float*)d_in[5];
  const float* b_out = (const float*)d_in[6];
  lstm_kernel<<<B_ / NB, 512, 0, stream>>>(x, W_ih, W_hh, b_ih, b_hh,
                                           W_out, b_out, (float*)d_out);
}